// Round 1
// baseline (17460.657 us; speedup 1.0000x reference)
//
#include <hip/hip_runtime.h>

// Problem constants
#define W 128
#define H 64
#define HW 8192
#define NB 8
#define CF 629                 // final feat channels
#define FSTRIDE (CF * HW)      // per-batch stride in feat buffer

__device__ __forceinline__ float leakyf(float v) { return v >= 0.f ? v : 0.1f * v; }

// ---------------------------------------------------------------------------
// ConvTranspose2d k=4 s=2 p=1, Cout=2 (PyTorch weight layout (Cin,2,4,4)).
// One thread per output pixel (b,y,x), computes both output channels.
// out[b,co,y,x] = bias[co] + sum_ci sum_(ky,kx) in[b,ci,(y+1-ky)/2,(x+1-kx)/2] * w[ci,co,ky,kx]
// ---------------------------------------------------------------------------
__global__ void upconv2_kernel(const float* __restrict__ in, int Cin, int Hin, int Win,
                               const float* __restrict__ w, const float* __restrict__ bias,
                               float* __restrict__ out, long obs)
{
    const int x = threadIdx.x;   // 0..127
    const int y = blockIdx.x;    // 0..63
    const int b = blockIdx.y;    // 0..7

    // Valid taps: ky in {p, p+2} with p=(y+1)&1 (parity), same for x.
    const int p = (y + 1) & 1;
    const int kyA = p, kyB = p + 2;
    const int iyA = (y + 1 - kyA) >> 1;
    const int iyB = (y + 1 - kyB) >> 1;
    const bool vyA = (iyA >= 0) && (iyA < Hin);
    const bool vyB = (iyB >= 0) && (iyB < Hin);

    const int q = (x + 1) & 1;
    const int kxA = q, kxB = q + 2;
    const int ixA = (x + 1 - kxA) >> 1;
    const int ixB = (x + 1 - kxB) >> 1;
    const bool vxA = (ixA >= 0) && (ixA < Win);
    const bool vxB = (ixB >= 0) && (ixB < Win);

    const bool mAA = vyA && vxA, mAB = vyA && vxB, mBA = vyB && vxA, mBB = vyB && vxB;
    const int oAA = iyA * Win + ixA, oAB = iyA * Win + ixB;
    const int oBA = iyB * Win + ixA, oBB = iyB * Win + ixB;
    const int wAA = kyA * 4 + kxA, wAB = kyA * 4 + kxB;
    const int wBA = kyB * 4 + kxA, wBB = kyB * 4 + kxB;

    float acc0 = bias[0];
    float acc1 = bias[1];
    const long hwin = (long)Hin * Win;
    const float* ip = in + (long)b * Cin * hwin;
    const float* wp = w;
    for (int ci = 0; ci < Cin; ++ci, ip += hwin, wp += 32) {
        float vAA = mAA ? ip[oAA] : 0.f;
        float vAB = mAB ? ip[oAB] : 0.f;
        float vBA = mBA ? ip[oBA] : 0.f;
        float vBB = mBB ? ip[oBB] : 0.f;
        acc0 += vAA * wp[wAA] + vAB * wp[wAB] + vBA * wp[wBA] + vBB * wp[wBB];
        acc1 += vAA * wp[16 + wAA] + vAB * wp[16 + wAB] + vBA * wp[16 + wBA] + vBB * wp[16 + wBB];
    }
    long o = (long)b * obs + y * W + x;
    out[o]      = acc0;
    out[o + HW] = acc1;
}

// ---------------------------------------------------------------------------
// Bilinear warp of tenTwo by 1.25*tenFlow (zeros padding, align_corners=True).
// Flow is read from feat channels 625 (x) and 626 (y).
// ---------------------------------------------------------------------------
__global__ void warp_kernel(const float* __restrict__ tenTwo, const float* __restrict__ feat,
                            float* __restrict__ warped)
{
    const int x = threadIdx.x;
    const int y = blockIdx.x;
    const int b = blockIdx.y;

    const long fb = (long)b * FSTRIDE + 625L * HW + y * W + x;
    const float px = (float)x + 1.25f * feat[fb];
    const float py = (float)y + 1.25f * feat[fb + HW];

    const float x0f = floorf(px), y0f = floorf(py);
    const float wx = px - x0f, wy = py - y0f;
    const int x0 = (int)x0f, y0 = (int)y0f;
    const int x1 = x0 + 1,   y1 = y0 + 1;

    const bool vx0 = (x0 >= 0) && (x0 < W), vx1 = (x1 >= 0) && (x1 < W);
    const bool vy0 = (y0 >= 0) && (y0 < H), vy1 = (y1 >= 0) && (y1 < H);
    const int cx0 = min(max(x0, 0), W - 1), cx1 = min(max(x1, 0), W - 1);
    const int cy0 = min(max(y0, 0), H - 1), cy1 = min(max(y1, 0), H - 1);

    const float w00 = (1.f - wy) * (1.f - wx) * ((vy0 && vx0) ? 1.f : 0.f);
    const float w01 = (1.f - wy) * wx         * ((vy0 && vx1) ? 1.f : 0.f);
    const float w10 = wy * (1.f - wx)         * ((vy1 && vx0) ? 1.f : 0.f);
    const float w11 = wy * wx                 * ((vy1 && vx1) ? 1.f : 0.f);

    const int o00 = cy0 * W + cx0, o01 = cy0 * W + cx1;
    const int o10 = cy1 * W + cx0, o11 = cy1 * W + cx1;

    const long base = (long)b * 96 * HW;
    const long ob = base + y * W + x;
    for (int c = 0; c < 96; ++c) {
        const float* p = tenTwo + base + (long)c * HW;
        warped[ob + (long)c * HW] = p[o00] * w00 + p[o01] * w01 + p[o10] * w10 + p[o11] * w11;
    }
}

// ---------------------------------------------------------------------------
// Cost volume: vol[b, dy*9+dx, y, x] = leaky(mean_c one[b,c,y,x]*warped[b,c,y+dy-4,x+dx-4])
// Written to feat channels 448..528.
// ---------------------------------------------------------------------------
__global__ void corr_kernel(const float* __restrict__ one, const float* __restrict__ warped,
                            float* __restrict__ feat)
{
    const int x = threadIdx.x;
    const int y = blockIdx.x;
    const int k = blockIdx.y;   // 0..80
    const int b = blockIdx.z;
    const int dy = k / 9 - 4, dx = k % 9 - 4;
    const int yy = y + dy, xx = x + dx;

    float acc = 0.f;
    if (yy >= 0 && yy < H && xx >= 0 && xx < W) {
        const float* p1 = one    + (long)b * 96 * HW + y  * W + x;
        const float* p2 = warped + (long)b * 96 * HW + yy * W + xx;
        for (int c = 0; c < 96; ++c)
            acc += p1[(long)c * HW] * p2[(long)c * HW];
    }
    acc *= (1.f / 96.f);
    feat[(long)b * FSTRIDE + (long)(448 + k) * HW + y * W + x] = leakyf(acc);
}

// ---------------------------------------------------------------------------
// Copy tenOne into feat channels 529..624 (float4 vectorized)
// ---------------------------------------------------------------------------
__global__ void copy_one_kernel(const float* __restrict__ src, float* __restrict__ feat)
{
    const long tid = (long)blockIdx.x * 256 + threadIdx.x;   // over B*96*HW/4 float4s
    const long per_b = 96L * HW / 4;
    const long b = tid / per_b;
    const long r = tid - b * per_b;
    const float4 v = ((const float4*)src)[tid];
    ((float4*)(feat + b * (long)FSTRIDE + 529L * HW))[r] = v;
}

// ---------------------------------------------------------------------------
// Direct 3x3 conv, stride 1, pad 1 (zeros), + leaky. Each thread computes a
// 4-wide x strip for one (b, co, y). Block (32,8): one y-tile of 8 rows.
// Weight reads are block-uniform -> scalar loads.
// ---------------------------------------------------------------------------
__global__ __launch_bounds__(256) void conv3x3_kernel(
    const float* __restrict__ in, long ibs, int Cin,
    const float* __restrict__ w, const float* __restrict__ bias,
    float* __restrict__ out, long obs)
{
    const int tx = threadIdx.x;             // 0..31
    const int x0 = tx * 4;
    const int y  = (int)blockIdx.x * 8 + threadIdx.y;
    const int co = blockIdx.y;
    const int b  = blockIdx.z;

    const float* ip = in + (long)b * ibs + y * W + x0;
    const float* wb = w + (long)co * Cin * 9;

    const float bv = bias[co];
    float a0 = bv, a1 = bv, a2 = bv, a3 = bv;

    const bool xm0 = (tx > 0);
    const bool xm2 = (tx < 31);
    const bool ym0 = (y > 0);
    const bool ym2 = (y < H - 1);

    for (int ci = 0; ci < Cin; ++ci) {
        const float* p  = ip + (long)ci * HW;
        const float* wc = wb + ci * 9;
        #pragma unroll
        for (int ky = 0; ky < 3; ++ky) {
            if (ky == 0 && !ym0) continue;
            if (ky == 2 && !ym2) continue;
            const float* r = p + (ky - 1) * W;
            const float w0 = wc[ky * 3 + 0];
            const float w1 = wc[ky * 3 + 1];
            const float w2 = wc[ky * 3 + 2];
            const float4 v = *(const float4*)r;
            const float lft = xm0 ? r[-1] : 0.f;
            const float rgt = xm2 ? r[4]  : 0.f;
            a0 += lft * w0 + v.x * w1 + v.y * w2;
            a1 += v.x * w0 + v.y * w1 + v.z * w2;
            a2 += v.y * w0 + v.z * w1 + v.w * w2;
            a3 += v.z * w0 + v.w * w1 + rgt * w2;
        }
    }

    float4 o;
    o.x = leakyf(a0); o.y = leakyf(a1); o.z = leakyf(a2); o.w = leakyf(a3);
    *(float4*)(out + (long)b * obs + (long)co * HW + y * W + x0) = o;
}

// ---------------------------------------------------------------------------
extern "C" void kernel_launch(void* const* d_in, const int* in_sizes, int n_in,
                              void* d_out, int out_size, void* d_ws, size_t ws_size,
                              hipStream_t stream)
{
    const float* tenOne    = (const float*)d_in[0];
    const float* tenTwo    = (const float*)d_in[1];
    const float* prev_flow = (const float*)d_in[2];
    const float* prev_feat = (const float*)d_in[3];
    const float* w_upflow  = (const float*)d_in[4];
    const float* b_upflow  = (const float*)d_in[5];
    const float* w_upfeat  = (const float*)d_in[6];
    const float* b_upfeat  = (const float*)d_in[7];
    const float* w1 = (const float*)d_in[8];  const float* b1 = (const float*)d_in[9];
    const float* w2 = (const float*)d_in[10]; const float* b2 = (const float*)d_in[11];
    const float* w3 = (const float*)d_in[12]; const float* b3 = (const float*)d_in[13];
    const float* w4 = (const float*)d_in[14]; const float* b4 = (const float*)d_in[15];
    const float* w5 = (const float*)d_in[16]; const float* b5 = (const float*)d_in[17];
    const float* w6 = (const float*)d_in[18]; const float* b6 = (const float*)d_in[19];

    float* flow_out = (float*)d_out;                 // (B,2,H,W) = 131072 floats
    float* feat     = flow_out + (long)NB * 2 * HW;  // (B,629,H,W)
    float* warped   = (float*)d_ws;                  // (B,96,H,W) = 24 MB scratch

    // Final feat channel layout: [c5 0..32 | c4 32..96 | c3 96..192 | c2 192..320 |
    //                             c1 320..448 | vol 448..529 | one 529..625 |
    //                             flow 625..627 | upfeat 627..629]

    // tenFlow -> feat[625:627]
    upconv2_kernel<<<dim3(H, NB), W, 0, stream>>>(prev_flow, 2, 32, 64,
                                                  w_upflow, b_upflow,
                                                  feat + 625L * HW, (long)FSTRIDE);
    // upFeat -> feat[627:629]
    upconv2_kernel<<<dim3(H, NB), W, 0, stream>>>(prev_feat, 661, 32, 64,
                                                  w_upfeat, b_upfeat,
                                                  feat + 627L * HW, (long)FSTRIDE);
    // tenOne -> feat[529:625]
    copy_one_kernel<<<(NB * 96 * HW / 4) / 256, 256, 0, stream>>>(tenOne, feat);

    // warp tenTwo by 1.25*tenFlow
    warp_kernel<<<dim3(H, NB), W, 0, stream>>>(tenTwo, feat, warped);

    // cost volume -> feat[448:529] (with leaky)
    corr_kernel<<<dim3(H, 81, NB), W, 0, stream>>>(tenOne, warped, feat);

    // Dense conv chain, each writes its block directly into feat
    conv3x3_kernel<<<dim3(H / 8, 128, NB), dim3(32, 8), 0, stream>>>(
        feat + 448L * HW, (long)FSTRIDE, 181, w1, b1, feat + 320L * HW, (long)FSTRIDE);
    conv3x3_kernel<<<dim3(H / 8, 128, NB), dim3(32, 8), 0, stream>>>(
        feat + 320L * HW, (long)FSTRIDE, 309, w2, b2, feat + 192L * HW, (long)FSTRIDE);
    conv3x3_kernel<<<dim3(H / 8, 96, NB), dim3(32, 8), 0, stream>>>(
        feat + 192L * HW, (long)FSTRIDE, 437, w3, b3, feat + 96L * HW, (long)FSTRIDE);
    conv3x3_kernel<<<dim3(H / 8, 64, NB), dim3(32, 8), 0, stream>>>(
        feat + 96L * HW, (long)FSTRIDE, 533, w4, b4, feat + 32L * HW, (long)FSTRIDE);
    conv3x3_kernel<<<dim3(H / 8, 32, NB), dim3(32, 8), 0, stream>>>(
        feat + 32L * HW, (long)FSTRIDE, 597, w5, b5, feat, (long)FSTRIDE);
    // conv6 -> flow output (also leaky — netSix is a ConvBlock)
    conv3x3_kernel<<<dim3(H / 8, 2, NB), dim3(32, 8), 0, stream>>>(
        feat, (long)FSTRIDE, 629, w6, b6, flow_out, (long)(2 * HW));
}

// Round 2
// 2033.426 us; speedup vs baseline: 8.5868x; 8.5868x over previous
//
#include <hip/hip_runtime.h>

#define W 128
#define H 64
#define HW 8192
#define NB 8
#define CFP 632                 // padded NHWC channel stride (629 -> 632, 16B-aligned)

typedef __attribute__((ext_vector_type(8))) short short8;
typedef __attribute__((ext_vector_type(4))) float floatx4;

__device__ __forceinline__ float leakyf(float v) { return v >= 0.f ? v : 0.1f * v; }

__device__ __forceinline__ unsigned short f2bf(float f) {
    unsigned u = __float_as_uint(f);
    u += 0x7FFF + ((u >> 16) & 1);          // RNE
    return (unsigned short)(u >> 16);
}
__device__ __forceinline__ float bf2f(unsigned short s) {
    return __uint_as_float((unsigned)s << 16);
}

// ---------------------------------------------------------------------------
// ConvTranspose2d k=4 s=2 p=1, Cout=2 (PyTorch layout (Cin,2,4,4)) -> fp32 NCHW
// ---------------------------------------------------------------------------
__global__ void upconv2_kernel(const float* __restrict__ in, int Cin, int Hin, int Win,
                               const float* __restrict__ w, const float* __restrict__ bias,
                               float* __restrict__ out, long obs)
{
    const int x = threadIdx.x;
    const int y = blockIdx.x;
    const int b = blockIdx.y;

    const int p = (y + 1) & 1;
    const int kyA = p, kyB = p + 2;
    const int iyA = (y + 1 - kyA) >> 1;
    const int iyB = (y + 1 - kyB) >> 1;
    const bool vyA = (iyA >= 0) && (iyA < Hin);
    const bool vyB = (iyB >= 0) && (iyB < Hin);

    const int q = (x + 1) & 1;
    const int kxA = q, kxB = q + 2;
    const int ixA = (x + 1 - kxA) >> 1;
    const int ixB = (x + 1 - kxB) >> 1;
    const bool vxA = (ixA >= 0) && (ixA < Win);
    const bool vxB = (ixB >= 0) && (ixB < Win);

    const bool mAA = vyA && vxA, mAB = vyA && vxB, mBA = vyB && vxA, mBB = vyB && vxB;
    const int oAA = iyA * Win + ixA, oAB = iyA * Win + ixB;
    const int oBA = iyB * Win + ixA, oBB = iyB * Win + ixB;
    const int wAA = kyA * 4 + kxA, wAB = kyA * 4 + kxB;
    const int wBA = kyB * 4 + kxA, wBB = kyB * 4 + kxB;

    float acc0 = bias[0];
    float acc1 = bias[1];
    const long hwin = (long)Hin * Win;
    const float* ip = in + (long)b * Cin * hwin;
    const float* wp = w;
    for (int ci = 0; ci < Cin; ++ci, ip += hwin, wp += 32) {
        float vAA = mAA ? ip[oAA] : 0.f;
        float vAB = mAB ? ip[oAB] : 0.f;
        float vBA = mBA ? ip[oBA] : 0.f;
        float vBB = mBB ? ip[oBB] : 0.f;
        acc0 += vAA * wp[wAA] + vAB * wp[wAB] + vBA * wp[wBA] + vBB * wp[wBB];
        acc1 += vAA * wp[16 + wAA] + vAB * wp[16 + wAB] + vBA * wp[16 + wBA] + vBB * wp[16 + wBB];
    }
    long o = (long)b * obs + y * W + x;
    out[o]      = acc0;
    out[o + HW] = acc1;
}

// ---------------------------------------------------------------------------
// Bilinear warp (zeros padding) of tenTwo (NCHW fp32) by 1.25*flow4 -> fp32 NCHW
// ---------------------------------------------------------------------------
__global__ void warp_kernel(const float* __restrict__ tenTwo, const float* __restrict__ flow4,
                            float* __restrict__ warped)
{
    const int x = threadIdx.x;
    const int y = blockIdx.x;
    const int b = blockIdx.y;

    const long fb = (long)b * 2 * HW + y * W + x;
    const float px = (float)x + 1.25f * flow4[fb];
    const float py = (float)y + 1.25f * flow4[fb + HW];

    const float x0f = floorf(px), y0f = floorf(py);
    const float wx = px - x0f, wy = py - y0f;
    const int x0 = (int)x0f, y0 = (int)y0f;
    const int x1 = x0 + 1,   y1 = y0 + 1;

    const bool vx0 = (x0 >= 0) && (x0 < W), vx1 = (x1 >= 0) && (x1 < W);
    const bool vy0 = (y0 >= 0) && (y0 < H), vy1 = (y1 >= 0) && (y1 < H);
    const int cx0 = min(max(x0, 0), W - 1), cx1 = min(max(x1, 0), W - 1);
    const int cy0 = min(max(y0, 0), H - 1), cy1 = min(max(y1, 0), H - 1);

    const float w00 = (1.f - wy) * (1.f - wx) * ((vy0 && vx0) ? 1.f : 0.f);
    const float w01 = (1.f - wy) * wx         * ((vy0 && vx1) ? 1.f : 0.f);
    const float w10 = wy * (1.f - wx)         * ((vy1 && vx0) ? 1.f : 0.f);
    const float w11 = wy * wx                 * ((vy1 && vx1) ? 1.f : 0.f);

    const int o00 = cy0 * W + cx0, o01 = cy0 * W + cx1;
    const int o10 = cy1 * W + cx0, o11 = cy1 * W + cx1;

    const long base = (long)b * 96 * HW;
    const long ob = base + y * W + x;
    for (int c = 0; c < 96; ++c) {
        const float* p = tenTwo + base + (long)c * HW;
        warped[ob + (long)c * HW] = p[o00] * w00 + p[o01] * w01 + p[o10] * w10 + p[o11] * w11;
    }
}

// ---------------------------------------------------------------------------
// Cost volume (leaky applied) -> vol fp32 NCHW (B,81,H,W)
// ---------------------------------------------------------------------------
__global__ void corr_kernel(const float* __restrict__ one, const float* __restrict__ warped,
                            float* __restrict__ vol)
{
    const int x = threadIdx.x;
    const int y = blockIdx.x;
    const int k = blockIdx.y;   // 0..80
    const int b = blockIdx.z;
    const int dy = k / 9 - 4, dx = k % 9 - 4;
    const int yy = y + dy, xx = x + dx;

    float acc = 0.f;
    if (yy >= 0 && yy < H && xx >= 0 && xx < W) {
        const float* p1 = one    + (long)b * 96 * HW + y  * W + x;
        const float* p2 = warped + (long)b * 96 * HW + yy * W + xx;
        for (int c = 0; c < 96; ++c)
            acc += p1[(long)c * HW] * p2[(long)c * HW];
    }
    acc *= (1.f / 96.f);
    vol[((long)b * 81 + k) * HW + y * W + x] = leakyf(acc);
}

// ---------------------------------------------------------------------------
// Pack vol/tenOne/flow/upfeat (fp32 NCHW) into feat_nhwc bf16 channels 448..631
// ---------------------------------------------------------------------------
__global__ void pack_kernel(const float* __restrict__ vol, const float* __restrict__ one,
                            const float* __restrict__ flow4, const float* __restrict__ up4,
                            unsigned short* __restrict__ featn)
{
    const long t = (long)blockIdx.x * 256 + threadIdx.x;    // pixel index, 0..65535
    const long b = t >> 13;
    const long p = t & (HW - 1);
    unsigned short buf[8];
    for (int cc = 0; cc < 23; ++cc) {
        #pragma unroll
        for (int j = 0; j < 8; ++j) {
            const int c = 448 + cc * 8 + j;
            float v;
            if (c < 529)      v = vol[(b * 81 + (c - 448)) * HW + p];
            else if (c < 625) v = one[(b * 96 + (c - 529)) * HW + p];
            else if (c < 627) v = flow4[(b * 2 + (c - 625)) * HW + p];
            else if (c < 629) v = up4[(b * 2 + (c - 627)) * HW + p];
            else              v = 0.f;
            buf[j] = f2bf(v);
        }
        *(uint4*)(featn + t * CFP + 448 + cc * 8) = *(const uint4*)buf;
    }
}

// ---------------------------------------------------------------------------
// feat_nhwc bf16 -> d_out feat region fp32 NCHW (B,629,H,W)
// ---------------------------------------------------------------------------
__global__ void unpack_kernel(const unsigned short* __restrict__ featn, float* __restrict__ out)
{
    const long t = (long)blockIdx.x * 256 + threadIdx.x;    // pixel
    const long b = t >> 13;
    const long p = t & (HW - 1);
    const unsigned short* f = featn + t * CFP;
    float* ob = out + b * 629L * HW + p;
    for (int cc = 0; cc < 79; ++cc) {
        uint4 v = *(const uint4*)(f + cc * 8);
        unsigned short s[8];
        *(uint4*)s = v;
        #pragma unroll
        for (int j = 0; j < 8; ++j) {
            const int c = cc * 8 + j;
            if (c < 629) ob[(long)c * HW] = bf2f(s[j]);
        }
    }
}

// ---------------------------------------------------------------------------
// Weight convert: fp32 OIHW [co][ci][3][3] -> bf16 [co][tap][Kpad], zero-padded
// in both ci (>=Cin) and co (>=Cout).
// ---------------------------------------------------------------------------
__global__ void wcvt_kernel(const float* __restrict__ w, unsigned short* __restrict__ wt,
                            int Cout, int Cin, int Kpad, long total)
{
    const long t = (long)blockIdx.x * 256 + threadIdx.x;
    if (t >= total) return;
    const int ci = (int)(t % Kpad);
    const long r = t / Kpad;
    const int tap = (int)(r % 9);
    const int co = (int)(r / 9);
    float v = 0.f;
    if (co < Cout && ci < Cin) v = w[((long)co * Cin + ci) * 9 + tap];
    wt[t] = f2bf(v);
}

// ---------------------------------------------------------------------------
// Implicit-GEMM 3x3 conv, bf16 MFMA 16x16x32, fp32 accum.
// Block: 256 thr (4 waves) = one image row (M=128 px) x Cout tile (NF*16).
// K-loop: ci chunks of 32 (LDS-staged 3 rows x 130 px x 32ch) x 9 taps.
// Output: bf16 into feat_nhwc at oc0 (or fp32 NCHW flow for the last conv).
// ---------------------------------------------------------------------------
template<int NF>
__global__ __launch_bounds__(256) void conv_mfma(
    const unsigned short* __restrict__ featn, int c0, int Kpad,
    const unsigned short* __restrict__ wt, const float* __restrict__ bias,
    unsigned short* __restrict__ outf, int oc0, float* __restrict__ flowout)
{
    __shared__ unsigned short tile[3 * 130 * 40];   // [r][xx(0..129)][ch pad 40]

    const int row = blockIdx.x;          // b*H + y
    const int b = row >> 6;
    const int y = row & 63;
    const int tid = threadIdx.x;
    const int lane = tid & 63;
    const int wv = tid >> 6;             // wave id, m-base = wv*32
    const int l15 = lane & 15;
    const int q = lane >> 4;

    floatx4 acc[2][NF];
    #pragma unroll
    for (int mf = 0; mf < 2; ++mf)
        #pragma unroll
        for (int nf = 0; nf < NF; ++nf)
            acc[mf][nf] = (floatx4){0.f, 0.f, 0.f, 0.f};

    const int wstride = 9 * Kpad;        // per-co weight stride (elements)
    const int nchunks = Kpad >> 5;

    for (int kc = 0; kc < nchunks; ++kc) {
        // ---- stage A chunk: 390 (r,xx) pairs x 32ch, as 8B units ----
        for (int u = tid; u < 3120; u += 256) {
            const int pr = u >> 3;       // pair index 0..389
            const int sub = u & 7;       // 4-ch unit within chunk
            const int r = (pr >= 260) ? 2 : (pr >= 130 ? 1 : 0);
            const int xx = pr - r * 130;
            const int gy = y + r - 1, gx = xx - 1;
            uint2 v = make_uint2(0u, 0u);
            if (gy >= 0 && gy < H && gx >= 0 && gx < W) {
                const long pix = (long)(b * H + gy) * W + gx;
                v = *(const uint2*)(featn + pix * CFP + c0 + kc * 32 + sub * 4);
            }
            *(uint2*)&tile[pr * 40 + sub * 4] = v;
        }
        __syncthreads();

        // ---- 9 taps, K=32 each ----
        #pragma unroll
        for (int ky = 0; ky < 3; ++ky) {
            #pragma unroll
            for (int kx = 0; kx < 3; ++kx) {
                const int tap = ky * 3 + kx;
                const short8 a0 = *(const short8*)&tile[(ky * 130 + wv * 32 + l15 + kx) * 40 + q * 8];
                const short8 a1 = *(const short8*)&tile[(ky * 130 + wv * 32 + 16 + l15 + kx) * 40 + q * 8];
                const unsigned short* wb = wt + (long)l15 * wstride + tap * Kpad + kc * 32 + q * 8;
                #pragma unroll
                for (int nf = 0; nf < NF; ++nf) {
                    const short8 bf = *(const short8*)(wb + (long)nf * 16 * wstride);
                    acc[0][nf] = __builtin_amdgcn_mfma_f32_16x16x32_bf16(a0, bf, acc[0][nf], 0, 0, 0);
                    acc[1][nf] = __builtin_amdgcn_mfma_f32_16x16x32_bf16(a1, bf, acc[1][nf], 0, 0, 0);
                }
            }
        }
        __syncthreads();
    }

    // ---- epilogue: bias + leaky, D layout m=q*4+r, n=l15 ----
    float bv[NF];
    #pragma unroll
    for (int nf = 0; nf < NF; ++nf) bv[nf] = bias[nf * 16 + l15];

    if (flowout == nullptr) {
        #pragma unroll
        for (int mf = 0; mf < 2; ++mf) {
            const int xb = wv * 32 + mf * 16 + q * 4;
            #pragma unroll
            for (int r = 0; r < 4; ++r) {
                const long pix = (long)row * W + xb + r;
                #pragma unroll
                for (int nf = 0; nf < NF; ++nf) {
                    float v = acc[mf][nf][r] + bv[nf];
                    outf[pix * CFP + oc0 + nf * 16 + l15] = f2bf(leakyf(v));
                }
            }
        }
    } else {
        // conv6: co = l15 (<2) -> fp32 NCHW flow output
        if (l15 < 2) {
            const float bb = bias[l15];
            #pragma unroll
            for (int mf = 0; mf < 2; ++mf) {
                const int xb = wv * 32 + mf * 16 + q * 4;
                #pragma unroll
                for (int r = 0; r < 4; ++r) {
                    float v = acc[mf][0][r] + bb;
                    flowout[((long)b * 2 + l15) * HW + y * W + xb + r] = leakyf(v);
                }
            }
        }
    }
}

// ---------------------------------------------------------------------------
extern "C" void kernel_launch(void* const* d_in, const int* in_sizes, int n_in,
                              void* d_out, int out_size, void* d_ws, size_t ws_size,
                              hipStream_t stream)
{
    const float* tenOne    = (const float*)d_in[0];
    const float* tenTwo    = (const float*)d_in[1];
    const float* prev_flow = (const float*)d_in[2];
    const float* prev_feat = (const float*)d_in[3];
    const float* w_upflow  = (const float*)d_in[4];
    const float* b_upflow  = (const float*)d_in[5];
    const float* w_upfeat  = (const float*)d_in[6];
    const float* b_upfeat  = (const float*)d_in[7];
    const float* wc[6] = {(const float*)d_in[8],  (const float*)d_in[10], (const float*)d_in[12],
                          (const float*)d_in[14], (const float*)d_in[16], (const float*)d_in[18]};
    const float* bc[6] = {(const float*)d_in[9],  (const float*)d_in[11], (const float*)d_in[13],
                          (const float*)d_in[15], (const float*)d_in[17], (const float*)d_in[19]};

    float* flow_out = (float*)d_out;                  // (B,2,H,W)
    float* feat_out = flow_out + (long)NB * 2 * HW;   // (B,629,H,W)

    // workspace layout (bytes)
    char* ws = (char*)d_ws;
    unsigned short* featn = (unsigned short*)ws;                    // 82,837,504 (+4K slack)
    float* warped = (float*)(ws + 82841600L);                       // 25,165,824
    float* vol    = (float*)(ws + 108007424L);                      // 21,233,664
    float* flow4  = (float*)(ws + 129241088L);                      // 524,288
    float* up4    = (float*)(ws + 129765376L);                      // 524,288
    unsigned short* wt1 = (unsigned short*)(ws + 130289664L);
    unsigned short* wt2 = (unsigned short*)(ws + 130732032L);
    unsigned short* wt3 = (unsigned short*)(ws + 131469312L);
    unsigned short* wt4 = (unsigned short*)(ws + 132243456L);
    unsigned short* wt5 = (unsigned short*)(ws + 132870144L);
    unsigned short* wt6 = (unsigned short*)(ws + 133220352L);
    unsigned short* wts[6] = {wt1, wt2, wt3, wt4, wt5, wt6};

    // per-conv configs: {Cout, Cin, Kpad, CoPad, c0, oc0}
    const int Cout[6] = {128, 128, 96, 64, 32, 2};
    const int Cin [6] = {181, 309, 437, 533, 597, 629};
    const int Kpad[6] = {192, 320, 448, 544, 608, 640};
    const int CoPd[6] = {128, 128, 96, 64, 32, 16};
    const int c0  [6] = {448, 320, 192, 96, 32, 0};
    const int oc0 [6] = {320, 192, 96, 32, 0, 0};

    // weight conversion
    for (int i = 0; i < 6; ++i) {
        long total = (long)CoPd[i] * 9 * Kpad[i];
        wcvt_kernel<<<(int)((total + 255) / 256), 256, 0, stream>>>(
            wc[i], wts[i], Cout[i], Cin[i], Kpad[i], total);
    }

    // upsample flow + feat
    upconv2_kernel<<<dim3(H, NB), W, 0, stream>>>(prev_flow, 2, 32, 64,
                                                  w_upflow, b_upflow, flow4, (long)(2 * HW));
    upconv2_kernel<<<dim3(H, NB), W, 0, stream>>>(prev_feat, 661, 32, 64,
                                                  w_upfeat, b_upfeat, up4, (long)(2 * HW));

    // warp + correlation
    warp_kernel<<<dim3(H, NB), W, 0, stream>>>(tenTwo, flow4, warped);
    corr_kernel<<<dim3(H, 81, NB), W, 0, stream>>>(tenOne, warped, vol);

    // pack channels 448..631 into NHWC bf16
    pack_kernel<<<256, 256, 0, stream>>>(vol, tenOne, flow4, up4, featn);

    // conv chain (MFMA)
    conv_mfma<8><<<512, 256, 0, stream>>>(featn, c0[0], Kpad[0], wts[0], bc[0], featn, oc0[0], nullptr);
    conv_mfma<8><<<512, 256, 0, stream>>>(featn, c0[1], Kpad[1], wts[1], bc[1], featn, oc0[1], nullptr);
    conv_mfma<6><<<512, 256, 0, stream>>>(featn, c0[2], Kpad[2], wts[2], bc[2], featn, oc0[2], nullptr);
    conv_mfma<4><<<512, 256, 0, stream>>>(featn, c0[3], Kpad[3], wts[3], bc[3], featn, oc0[3], nullptr);
    conv_mfma<2><<<512, 256, 0, stream>>>(featn, c0[4], Kpad[4], wts[4], bc[4], featn, oc0[4], nullptr);
    conv_mfma<1><<<512, 256, 0, stream>>>(featn, c0[5], Kpad[5], wts[5], bc[5], featn, 0, flow_out);

    // unpack feat to fp32 NCHW output
    unpack_kernel<<<256, 256, 0, stream>>>(featn, feat_out);
}

// Round 3
// 1836.993 us; speedup vs baseline: 9.5050x; 1.1069x over previous
//
#include <hip/hip_runtime.h>

#define W 128
#define H 64
#define HW 8192
#define NB 8
#define CFP 632                 // padded NHWC channel stride (629 -> 632, 16B-aligned)

typedef __attribute__((ext_vector_type(8))) short short8;
typedef __attribute__((ext_vector_type(4))) float floatx4;

__device__ __forceinline__ float leakyf(float v) { return v >= 0.f ? v : 0.1f * v; }

__device__ __forceinline__ unsigned short f2bf(float f) {
    unsigned u = __float_as_uint(f);
    u += 0x7FFF + ((u >> 16) & 1);          // RNE
    return (unsigned short)(u >> 16);
}
__device__ __forceinline__ float bf2f(unsigned short s) {
    return __uint_as_float((unsigned)s << 16);
}

// ---------------------------------------------------------------------------
// ConvTranspose2d k=4 s=2 p=1, Cout=2, small Cin (used for prev_flow, Cin=2)
// ---------------------------------------------------------------------------
__global__ void upconv2_kernel(const float* __restrict__ in, int Cin, int Hin, int Win,
                               const float* __restrict__ w, const float* __restrict__ bias,
                               float* __restrict__ out, long obs)
{
    const int x = threadIdx.x;
    const int y = blockIdx.x;
    const int b = blockIdx.y;

    const int p = (y + 1) & 1;
    const int kyA = p, kyB = p + 2;
    const int iyA = (y + 1 - kyA) >> 1;
    const int iyB = (y + 1 - kyB) >> 1;
    const bool vyA = (iyA >= 0) && (iyA < Hin);
    const bool vyB = (iyB >= 0) && (iyB < Hin);

    const int q = (x + 1) & 1;
    const int kxA = q, kxB = q + 2;
    const int ixA = (x + 1 - kxA) >> 1;
    const int ixB = (x + 1 - kxB) >> 1;
    const bool vxA = (ixA >= 0) && (ixA < Win);
    const bool vxB = (ixB >= 0) && (ixB < Win);

    const bool mAA = vyA && vxA, mAB = vyA && vxB, mBA = vyB && vxA, mBB = vyB && vxB;
    const int oAA = iyA * Win + ixA, oAB = iyA * Win + ixB;
    const int oBA = iyB * Win + ixA, oBB = iyB * Win + ixB;
    const int wAA = kyA * 4 + kxA, wAB = kyA * 4 + kxB;
    const int wBA = kyB * 4 + kxA, wBB = kyB * 4 + kxB;

    float acc0 = bias[0];
    float acc1 = bias[1];
    const long hwin = (long)Hin * Win;
    const float* ip = in + (long)b * Cin * hwin;
    const float* wp = w;
    for (int ci = 0; ci < Cin; ++ci, ip += hwin, wp += 32) {
        float vAA = mAA ? ip[oAA] : 0.f;
        float vAB = mAB ? ip[oAB] : 0.f;
        float vBA = mBA ? ip[oBA] : 0.f;
        float vBB = mBB ? ip[oBB] : 0.f;
        acc0 += vAA * wp[wAA] + vAB * wp[wAB] + vBA * wp[wBA] + vBB * wp[wBB];
        acc1 += vAA * wp[16 + wAA] + vAB * wp[16 + wAB] + vBA * wp[16 + wBA] + vBB * wp[16 + wBB];
    }
    long o = (long)b * obs + y * W + x;
    out[o]      = acc0;
    out[o + HW] = acc1;
}

// ---------------------------------------------------------------------------
// Same transpose-conv, Cin split 8 ways within a 1024-thread block (latency fix
// for Cin=661). LDS reduce; s==0 group adds bias and stores.
// ---------------------------------------------------------------------------
__global__ __launch_bounds__(1024) void upconv2_split_kernel(
    const float* __restrict__ in, int Cin, int Hin, int Win,
    const float* __restrict__ w, const float* __restrict__ bias,
    float* __restrict__ out, long obs)
{
    __shared__ float red[8][128][2];

    const int x = threadIdx.x & 127;
    const int s = threadIdx.x >> 7;       // split 0..7 (wave-uniform)
    const int y = blockIdx.x;
    const int b = blockIdx.y;

    const int p = (y + 1) & 1;
    const int kyA = p, kyB = p + 2;
    const int iyA = (y + 1 - kyA) >> 1;
    const int iyB = (y + 1 - kyB) >> 1;
    const bool vyA = (iyA >= 0) && (iyA < Hin);
    const bool vyB = (iyB >= 0) && (iyB < Hin);

    const int q = (x + 1) & 1;
    const int kxA = q, kxB = q + 2;
    const int ixA = (x + 1 - kxA) >> 1;
    const int ixB = (x + 1 - kxB) >> 1;
    const bool vxA = (ixA >= 0) && (ixA < Win);
    const bool vxB = (ixB >= 0) && (ixB < Win);

    const bool mAA = vyA && vxA, mAB = vyA && vxB, mBA = vyB && vxA, mBB = vyB && vxB;
    const int oAA = iyA * Win + ixA, oAB = iyA * Win + ixB;
    const int oBA = iyB * Win + ixA, oBB = iyB * Win + ixB;
    const int wAA = kyA * 4 + kxA, wAB = kyA * 4 + kxB;
    const int wBA = kyB * 4 + kxA, wBB = kyB * 4 + kxB;

    const int per = (Cin + 7) / 8;
    const int lo = s * per;
    const int hi = min(lo + per, Cin);

    float acc0 = 0.f, acc1 = 0.f;
    const long hwin = (long)Hin * Win;
    const float* ip = in + (long)b * Cin * hwin + (long)lo * hwin;
    const float* wp = w + lo * 32;
    for (int ci = lo; ci < hi; ++ci, ip += hwin, wp += 32) {
        float vAA = mAA ? ip[oAA] : 0.f;
        float vAB = mAB ? ip[oAB] : 0.f;
        float vBA = mBA ? ip[oBA] : 0.f;
        float vBB = mBB ? ip[oBB] : 0.f;
        acc0 += vAA * wp[wAA] + vAB * wp[wAB] + vBA * wp[wBA] + vBB * wp[wBB];
        acc1 += vAA * wp[16 + wAA] + vAB * wp[16 + wAB] + vBA * wp[16 + wBA] + vBB * wp[16 + wBB];
    }
    red[s][x][0] = acc0;
    red[s][x][1] = acc1;
    __syncthreads();
    if (s == 0) {
        float a0 = bias[0], a1 = bias[1];
        #pragma unroll
        for (int t = 0; t < 8; ++t) { a0 += red[t][x][0]; a1 += red[t][x][1]; }
        long o = (long)b * obs + y * W + x;
        out[o]      = a0;
        out[o + HW] = a1;
    }
}

// ---------------------------------------------------------------------------
// Bilinear warp (zeros padding) -> warped_n NHWC bf16 (pitch 96).
// Block = 512 threads: 4 channel-splits x 128 px (one image row).
// LDS transpose so global stores are coalesced uint4.
// ---------------------------------------------------------------------------
__global__ __launch_bounds__(512) void warp_nhwc_kernel(
    const float* __restrict__ tenTwo, const float* __restrict__ flow4,
    unsigned short* __restrict__ warped_n)
{
    __shared__ unsigned short tile[128 * 98];   // pitch 98 shorts: conflict-free b16 stores

    const int x   = threadIdx.x & 127;
    const int sub = threadIdx.x >> 7;           // 0..3, 24 channels each
    const int row = blockIdx.x;                 // b*H + y
    const int b = row >> 6;
    const int y = row & 63;

    const long fb = (long)b * 2 * HW + y * W + x;
    const float px = (float)x + 1.25f * flow4[fb];
    const float py = (float)y + 1.25f * flow4[fb + HW];

    const float x0f = floorf(px), y0f = floorf(py);
    const float wx = px - x0f, wy = py - y0f;
    const int x0 = (int)x0f, y0 = (int)y0f;
    const int x1 = x0 + 1,   y1 = y0 + 1;

    const bool vx0 = (x0 >= 0) && (x0 < W), vx1 = (x1 >= 0) && (x1 < W);
    const bool vy0 = (y0 >= 0) && (y0 < H), vy1 = (y1 >= 0) && (y1 < H);
    const int cx0 = min(max(x0, 0), W - 1), cx1 = min(max(x1, 0), W - 1);
    const int cy0 = min(max(y0, 0), H - 1), cy1 = min(max(y1, 0), H - 1);

    const float w00 = (1.f - wy) * (1.f - wx) * ((vy0 && vx0) ? 1.f : 0.f);
    const float w01 = (1.f - wy) * wx         * ((vy0 && vx1) ? 1.f : 0.f);
    const float w10 = wy * (1.f - wx)         * ((vy1 && vx0) ? 1.f : 0.f);
    const float w11 = wy * wx                 * ((vy1 && vx1) ? 1.f : 0.f);

    const int o00 = cy0 * W + cx0, o01 = cy0 * W + cx1;
    const int o10 = cy1 * W + cx0, o11 = cy1 * W + cx1;

    const long base = (long)b * 96 * HW + y * W;  // unused y part for taps; offsets absolute below
    for (int i = 0; i < 24; ++i) {
        const int c = sub * 24 + i;
        const float* pch = tenTwo + (long)(b * 96 + c) * HW;
        const float v = pch[o00] * w00 + pch[o01] * w01 + pch[o10] * w10 + pch[o11] * w11;
        tile[x * 98 + c] = f2bf(v);
    }
    __syncthreads();

    // write out 128 px x 96 ch = 1536 uint4
    unsigned short* op = warped_n + (long)row * 128 * 96;
    for (int u = threadIdx.x; u < 1536; u += 512) {
        const int pxi = u / 12;
        const int cc = u - pxi * 12;
        const unsigned short* tp = tile + pxi * 98 + cc * 8;
        uint4 v;
        v.x = *(const unsigned*)(tp + 0);
        v.y = *(const unsigned*)(tp + 2);
        v.z = *(const unsigned*)(tp + 4);
        v.w = *(const unsigned*)(tp + 6);
        *(uint4*)(op + u * 8) = v;
    }
}

// ---------------------------------------------------------------------------
// Cost volume from NHWC bf16 warped + NCHW fp32 tenOne (held in 96 VGPRs).
// Block = 512 threads: 4 tap-groups x 128 px (one row). Writes bf16 into
// featn channels 448..528 (with leaky).
// ---------------------------------------------------------------------------
__global__ __launch_bounds__(512) void corr_kernel(
    const float* __restrict__ tenOne, const unsigned short* __restrict__ warped_n,
    unsigned short* __restrict__ featn)
{
    const int x  = threadIdx.x & 127;
    const int kg = threadIdx.x >> 7;     // 0..3
    const int row = blockIdx.x;          // b*H + y
    const int b = row >> 6;
    const int y = row & 63;
    const long pix = (long)row * W + x;

    float one[96];
    const float* op = tenOne + (long)b * 96 * HW + y * W + x;
    #pragma unroll
    for (int j = 0; j < 96; ++j) one[j] = op[(long)j * HW];

    const int k0 = kg * 21;
    const int k1 = min(k0 + 21, 81);
    for (int k = k0; k < k1; ++k) {
        const int dy = k / 9 - 4, dx = k % 9 - 4;   // wave-uniform
        const int yy = y + dy, xx = x + dx;
        float acc = 0.f;
        if (yy >= 0 && yy < H && xx >= 0 && xx < W) {
            const unsigned short* wp = warped_n + ((long)(b * H + yy) * W + xx) * 96;
            #pragma unroll
            for (int c4 = 0; c4 < 12; ++c4) {
                const uint4 v = *(const uint4*)(wp + c4 * 8);
                unsigned uu[4] = {v.x, v.y, v.z, v.w};
                #pragma unroll
                for (int e = 0; e < 4; ++e) {
                    const float flo = __uint_as_float(uu[e] << 16);
                    const float fhi = __uint_as_float(uu[e] & 0xffff0000u);
                    acc += one[c4 * 8 + e * 2] * flo + one[c4 * 8 + e * 2 + 1] * fhi;
                }
            }
        }
        featn[pix * CFP + 448 + k] = f2bf(leakyf(acc * (1.f / 96.f)));
    }
}

// ---------------------------------------------------------------------------
// Pack tenOne/flow/upfeat (fp32) into featn bf16 channels 528..631.
// (528 is a placeholder overwritten later by corr; 629..631 are zero pad.)
// ---------------------------------------------------------------------------
__global__ void pack_kernel(const float* __restrict__ one, const float* __restrict__ flow4,
                            const float* __restrict__ up4, unsigned short* __restrict__ featn)
{
    const long t = (long)blockIdx.x * 256 + threadIdx.x;    // pixel 0..65535
    const long b = t >> 13;
    const long p = t & (HW - 1);
    unsigned short buf[8];
    for (int cc = 0; cc < 13; ++cc) {
        #pragma unroll
        for (int j = 0; j < 8; ++j) {
            const int c = 528 + cc * 8 + j;
            float v;
            if (c < 529)      v = 0.f;
            else if (c < 625) v = one[(b * 96 + (c - 529)) * HW + p];
            else if (c < 627) v = flow4[(b * 2 + (c - 625)) * HW + p];
            else if (c < 629) v = up4[(b * 2 + (c - 627)) * HW + p];
            else              v = 0.f;
            buf[j] = f2bf(v);
        }
        *(uint4*)(featn + t * CFP + 528 + cc * 8) = *(const uint4*)buf;
    }
}

// ---------------------------------------------------------------------------
// feat_nhwc bf16 -> d_out feat region fp32 NCHW (B,629,H,W)
// ---------------------------------------------------------------------------
__global__ void unpack_kernel(const unsigned short* __restrict__ featn, float* __restrict__ out)
{
    const long t = (long)blockIdx.x * 256 + threadIdx.x;    // pixel
    const long b = t >> 13;
    const long p = t & (HW - 1);
    const unsigned short* f = featn + t * CFP;
    float* ob = out + b * 629L * HW + p;
    for (int cc = 0; cc < 79; ++cc) {
        uint4 v = *(const uint4*)(f + cc * 8);
        unsigned short s[8];
        *(uint4*)s = v;
        #pragma unroll
        for (int j = 0; j < 8; ++j) {
            const int c = cc * 8 + j;
            if (c < 629) ob[(long)c * HW] = bf2f(s[j]);
        }
    }
}

// ---------------------------------------------------------------------------
// Weight convert: fp32 OIHW -> bf16 [co][tap][Kpad], zero-padded ci/co.
// ---------------------------------------------------------------------------
__global__ void wcvt_kernel(const float* __restrict__ w, unsigned short* __restrict__ wt,
                            int Cout, int Cin, int Kpad, long total)
{
    const long t = (long)blockIdx.x * 256 + threadIdx.x;
    if (t >= total) return;
    const int ci = (int)(t % Kpad);
    const long r = t / Kpad;
    const int tap = (int)(r % 9);
    const int co = (int)(r / 9);
    float v = 0.f;
    if (co < Cout && ci < Cin) v = w[((long)co * Cin + ci) * 9 + tap];
    wt[t] = f2bf(v);
}

// ---------------------------------------------------------------------------
// Implicit-GEMM 3x3 conv, bf16 MFMA 16x16x32, fp32 accum. (unchanged from R2)
// ---------------------------------------------------------------------------
template<int NF>
__global__ __launch_bounds__(256) void conv_mfma(
    const unsigned short* __restrict__ featn, int c0, int Kpad,
    const unsigned short* __restrict__ wt, const float* __restrict__ bias,
    unsigned short* __restrict__ outf, int oc0, float* __restrict__ flowout)
{
    __shared__ unsigned short tile[3 * 130 * 40];   // [r][xx(0..129)][ch pad 40]

    const int row = blockIdx.x;          // b*H + y
    const int b = row >> 6;
    const int y = row & 63;
    const int tid = threadIdx.x;
    const int lane = tid & 63;
    const int wv = tid >> 6;
    const int l15 = lane & 15;
    const int q = lane >> 4;

    floatx4 acc[2][NF];
    #pragma unroll
    for (int mf = 0; mf < 2; ++mf)
        #pragma unroll
        for (int nf = 0; nf < NF; ++nf)
            acc[mf][nf] = (floatx4){0.f, 0.f, 0.f, 0.f};

    const int wstride = 9 * Kpad;
    const int nchunks = Kpad >> 5;

    for (int kc = 0; kc < nchunks; ++kc) {
        for (int u = tid; u < 3120; u += 256) {
            const int pr = u >> 3;
            const int sub = u & 7;
            const int r = (pr >= 260) ? 2 : (pr >= 130 ? 1 : 0);
            const int xx = pr - r * 130;
            const int gy = y + r - 1, gx = xx - 1;
            uint2 v = make_uint2(0u, 0u);
            if (gy >= 0 && gy < H && gx >= 0 && gx < W) {
                const long pixg = (long)(b * H + gy) * W + gx;
                v = *(const uint2*)(featn + pixg * CFP + c0 + kc * 32 + sub * 4);
            }
            *(uint2*)&tile[pr * 40 + sub * 4] = v;
        }
        __syncthreads();

        #pragma unroll
        for (int ky = 0; ky < 3; ++ky) {
            #pragma unroll
            for (int kx = 0; kx < 3; ++kx) {
                const int tap = ky * 3 + kx;
                const short8 a0 = *(const short8*)&tile[(ky * 130 + wv * 32 + l15 + kx) * 40 + q * 8];
                const short8 a1 = *(const short8*)&tile[(ky * 130 + wv * 32 + 16 + l15 + kx) * 40 + q * 8];
                const unsigned short* wb = wt + (long)l15 * wstride + tap * Kpad + kc * 32 + q * 8;
                #pragma unroll
                for (int nf = 0; nf < NF; ++nf) {
                    const short8 bf = *(const short8*)(wb + (long)nf * 16 * wstride);
                    acc[0][nf] = __builtin_amdgcn_mfma_f32_16x16x32_bf16(a0, bf, acc[0][nf], 0, 0, 0);
                    acc[1][nf] = __builtin_amdgcn_mfma_f32_16x16x32_bf16(a1, bf, acc[1][nf], 0, 0, 0);
                }
            }
        }
        __syncthreads();
    }

    float bv[NF];
    #pragma unroll
    for (int nf = 0; nf < NF; ++nf) bv[nf] = bias[nf * 16 + l15];

    if (flowout == nullptr) {
        #pragma unroll
        for (int mf = 0; mf < 2; ++mf) {
            const int xb = wv * 32 + mf * 16 + q * 4;
            #pragma unroll
            for (int r = 0; r < 4; ++r) {
                const long pixo = (long)row * W + xb + r;
                #pragma unroll
                for (int nf = 0; nf < NF; ++nf) {
                    float v = acc[mf][nf][r] + bv[nf];
                    outf[pixo * CFP + oc0 + nf * 16 + l15] = f2bf(leakyf(v));
                }
            }
        }
    } else {
        if (l15 < 2) {
            const float bb = bias[l15];
            #pragma unroll
            for (int mf = 0; mf < 2; ++mf) {
                const int xb = wv * 32 + mf * 16 + q * 4;
                #pragma unroll
                for (int r = 0; r < 4; ++r) {
                    float v = acc[mf][0][r] + bb;
                    flowout[((long)b * 2 + l15) * HW + y * W + xb + r] = leakyf(v);
                }
            }
        }
    }
}

// ---------------------------------------------------------------------------
extern "C" void kernel_launch(void* const* d_in, const int* in_sizes, int n_in,
                              void* d_out, int out_size, void* d_ws, size_t ws_size,
                              hipStream_t stream)
{
    const float* tenOne    = (const float*)d_in[0];
    const float* tenTwo    = (const float*)d_in[1];
    const float* prev_flow = (const float*)d_in[2];
    const float* prev_feat = (const float*)d_in[3];
    const float* w_upflow  = (const float*)d_in[4];
    const float* b_upflow  = (const float*)d_in[5];
    const float* w_upfeat  = (const float*)d_in[6];
    const float* b_upfeat  = (const float*)d_in[7];
    const float* wc[6] = {(const float*)d_in[8],  (const float*)d_in[10], (const float*)d_in[12],
                          (const float*)d_in[14], (const float*)d_in[16], (const float*)d_in[18]};
    const float* bc[6] = {(const float*)d_in[9],  (const float*)d_in[11], (const float*)d_in[13],
                          (const float*)d_in[15], (const float*)d_in[17], (const float*)d_in[19]};

    float* flow_out = (float*)d_out;                  // (B,2,H,W)
    float* feat_out = flow_out + (long)NB * 2 * HW;   // (B,629,H,W)

    // workspace layout (bytes)
    char* ws = (char*)d_ws;
    unsigned short* featn    = (unsigned short*)ws;                 // 82,837,504 (+slack)
    unsigned short* warped_n = (unsigned short*)(ws + 82841600L);   // 12,582,912
    float* flow4 = (float*)(ws + 95424512L);                        // 524,288
    float* up4   = (float*)(ws + 95948800L);                        // 524,288
    unsigned short* wt1 = (unsigned short*)(ws + 96473088L);
    unsigned short* wt2 = (unsigned short*)(ws + 96915456L);
    unsigned short* wt3 = (unsigned short*)(ws + 97652736L);
    unsigned short* wt4 = (unsigned short*)(ws + 98426880L);
    unsigned short* wt5 = (unsigned short*)(ws + 99053568L);
    unsigned short* wt6 = (unsigned short*)(ws + 99403776L);
    unsigned short* wts[6] = {wt1, wt2, wt3, wt4, wt5, wt6};

    const int Cout[6] = {128, 128, 96, 64, 32, 2};
    const int Cin [6] = {181, 309, 437, 533, 597, 629};
    const int Kpad[6] = {192, 320, 448, 544, 608, 640};
    const int CoPd[6] = {128, 128, 96, 64, 32, 16};
    const int c0  [6] = {448, 320, 192, 96, 32, 0};
    const int oc0 [6] = {320, 192, 96, 32, 0, 0};

    for (int i = 0; i < 6; ++i) {
        long total = (long)CoPd[i] * 9 * Kpad[i];
        wcvt_kernel<<<(int)((total + 255) / 256), 256, 0, stream>>>(
            wc[i], wts[i], Cout[i], Cin[i], Kpad[i], total);
    }

    // upsample flow (small) + feat (split-reduce)
    upconv2_kernel<<<dim3(H, NB), W, 0, stream>>>(prev_flow, 2, 32, 64,
                                                  w_upflow, b_upflow, flow4, (long)(2 * HW));
    upconv2_split_kernel<<<dim3(H, NB), 1024, 0, stream>>>(prev_feat, 661, 32, 64,
                                                           w_upfeat, b_upfeat, up4, (long)(2 * HW));

    // pack static channels, warp, correlation
    pack_kernel<<<256, 256, 0, stream>>>(tenOne, flow4, up4, featn);
    warp_nhwc_kernel<<<512, 512, 0, stream>>>(tenTwo, flow4, warped_n);
    corr_kernel<<<512, 512, 0, stream>>>(tenOne, warped_n, featn);

    // conv chain (MFMA)
    conv_mfma<8><<<512, 256, 0, stream>>>(featn, c0[0], Kpad[0], wts[0], bc[0], featn, oc0[0], nullptr);
    conv_mfma<8><<<512, 256, 0, stream>>>(featn, c0[1], Kpad[1], wts[1], bc[1], featn, oc0[1], nullptr);
    conv_mfma<6><<<512, 256, 0, stream>>>(featn, c0[2], Kpad[2], wts[2], bc[2], featn, oc0[2], nullptr);
    conv_mfma<4><<<512, 256, 0, stream>>>(featn, c0[3], Kpad[3], wts[3], bc[3], featn, oc0[3], nullptr);
    conv_mfma<2><<<512, 256, 0, stream>>>(featn, c0[4], Kpad[4], wts[4], bc[4], featn, oc0[4], nullptr);
    conv_mfma<1><<<512, 256, 0, stream>>>(featn, c0[5], Kpad[5], wts[5], bc[5], featn, 0, flow_out);

    // unpack feat to fp32 NCHW output
    unpack_kernel<<<256, 256, 0, stream>>>(featn, feat_out);
}